// Round 1
// baseline (544.537 us; speedup 1.0000x reference)
//
#include <hip/hip_runtime.h>
#include <hip/hip_bf16.h>

#define EPSILON 0.01f

// Pass 1: msg_t[e,i] = sum_j B[e][j][i] * x[row[e]][j], scatter-add to ATx[col[e]]
// 4 lanes per edge; lane j holds B-row j (float4, coalesced load).
__global__ void __launch_bounds__(256) spmvt_kernel(
    const float4* __restrict__ boo,   // [E*4] rows of B
    const int* __restrict__ row,
    const int* __restrict__ col,
    const float* __restrict__ x,      // [N*4]
    float* __restrict__ ATx,          // [N*4], pre-zeroed
    long long E)
{
    long long t = (long long)blockIdx.x * blockDim.x + threadIdx.x;
    long long e = t >> 2;
    int j = (int)(t & 3);
    if (e >= E) return;

    float4 b = boo[e * 4 + j];            // B[e][j][0..3]
    int r = row[e];
    float xj = x[r * 4 + j];

    // partial contribution of row j to msg_t components i=0..3
    float4 p;
    p.x = b.x * xj; p.y = b.y * xj; p.z = b.z * xj; p.w = b.w * xj;

    // butterfly sum over the 4 lanes of the group (lane-aligned since blockDim%64==0)
    p.x += __shfl_xor(p.x, 1); p.y += __shfl_xor(p.y, 1);
    p.z += __shfl_xor(p.z, 1); p.w += __shfl_xor(p.w, 1);
    p.x += __shfl_xor(p.x, 2); p.y += __shfl_xor(p.y, 2);
    p.z += __shfl_xor(p.z, 2); p.w += __shfl_xor(p.w, 2);

    // all 4 lanes now hold full msg_t; lane j commits component j
    float v = (j == 0) ? p.x : (j == 1) ? p.y : (j == 2) ? p.z : p.w;
    int c = col[e];
    unsafeAtomicAdd(&ATx[c * 4 + j], v);
}

// Node pass: v = ATx * mask * diag (in place); out = EPSILON * x * diag
__global__ void __launch_bounds__(256) scale_init_kernel(
    const float* __restrict__ x,
    const float* __restrict__ mask,
    const float* __restrict__ diag,
    float* __restrict__ ATx,
    float* __restrict__ out,
    int N)
{
    int n = blockIdx.x * blockDim.x + threadIdx.x;
    if (n >= N) return;
    const float4* x4 = (const float4*)x;
    const float4* d4 = (const float4*)diag;
    float4* a4 = (float4*)ATx;
    float4* o4 = (float4*)out;

    float m = mask[n];
    float4 xv = x4[n];
    float4 dv = d4[n];
    float4 av = a4[n];

    float4 ov;
    ov.x = EPSILON * xv.x * dv.x; ov.y = EPSILON * xv.y * dv.y;
    ov.z = EPSILON * xv.z * dv.z; ov.w = EPSILON * xv.w * dv.w;
    o4[n] = ov;

    float4 sv;
    sv.x = av.x * dv.x * m; sv.y = av.y * dv.y * m;
    sv.z = av.z * dv.z * m; sv.w = av.w * dv.w * m;
    a4[n] = sv;
}

// Pass 2: msg[e,i] = dot(B[e][i][:], v[col[e]]), scatter-add mask[row]*msg to out[row]
__global__ void __launch_bounds__(256) spmv_kernel(
    const float4* __restrict__ boo,
    const int* __restrict__ row,
    const int* __restrict__ col,
    const float* __restrict__ vv,     // scaled ATx, [N*4]
    const float* __restrict__ mask,
    float* __restrict__ out,          // pre-initialized with eps*x*diag
    long long E)
{
    long long t = (long long)blockIdx.x * blockDim.x + threadIdx.x;
    long long e = t >> 2;
    int i = (int)(t & 3);
    if (e >= E) return;

    float4 b = boo[e * 4 + i];        // B[e][i][0..3]
    int c = col[e];
    const float4* v4 = (const float4*)vv;
    float4 v = v4[c];

    float mi = b.x * v.x + b.y * v.y + b.z * v.z + b.w * v.w;
    int r = row[e];
    float mr = mask[r];
    unsafeAtomicAdd(&out[r * 4 + i], mi * mr);
}

extern "C" void kernel_launch(void* const* d_in, const int* in_sizes, int n_in,
                              void* d_out, int out_size, void* d_ws, size_t ws_size,
                              hipStream_t stream) {
    const float* x    = (const float*)d_in[0];
    const int*   ei   = (const int*)d_in[1];
    const float* boo  = (const float*)d_in[2];
    const float* mask = (const float*)d_in[3];
    const float* diag = (const float*)d_in[4];
    float* out = (float*)d_out;

    int N = in_sizes[0] / 4;
    long long E = in_sizes[1] / 2;
    const int* row = ei;
    const int* col = ei + E;
    float* ATx = (float*)d_ws;

    // zero the accumulator (ws is poisoned with 0xAA before every launch)
    hipMemsetAsync(ATx, 0, (size_t)N * 4 * sizeof(float), stream);

    const int blk = 256;
    long long T = E * 4;
    int gEdge = (int)((T + blk - 1) / blk);
    int gNode = (N + blk - 1) / blk;

    spmvt_kernel<<<gEdge, blk, 0, stream>>>(
        (const float4*)boo, row, col, x, ATx, E);
    scale_init_kernel<<<gNode, blk, 0, stream>>>(
        x, mask, diag, ATx, out, N);
    spmv_kernel<<<gEdge, blk, 0, stream>>>(
        (const float4*)boo, row, col, ATx, mask, out, E);
}